// Round 4
// baseline (602.916 us; speedup 1.0000x reference)
//
#include <hip/hip_runtime.h>
#include <math.h>

// Problem constants: B=1024, T=256, D=128, H=64, 4H=256
constexpr int B_ = 1024;
constexpr int T_ = 256;
constexpr int D_ = 128;
constexpr int H_ = 64;
constexpr int G_ = 4 * H_;        // 256 gate rows
constexpr int M_ = B_ * T_;

typedef short  v8s  __attribute__((ext_vector_type(8)));   // 8 bf16 (4 VGPRs)
typedef float  v4f  __attribute__((ext_vector_type(4)));   // MFMA acc

__device__ __forceinline__ float sigmoidf_(float x) {
    return 1.0f / (1.0f + __expf(-x));
}
// tanh(x) = 2*sigmoid(2x) - 1 ; overflow-safe at both ends
__device__ __forceinline__ float tanhf_(float x) {
    return fmaf(2.0f, 1.0f / (1.0f + __expf(-2.0f * x)), -1.0f);
}
__device__ __forceinline__ unsigned short f2bf(float f) {   // RNE f32->bf16
    unsigned u = __float_as_uint(f);
    u = (u + 0x7fffu + ((u >> 16) & 1u)) >> 16;
    return (unsigned short)u;
}
__device__ __forceinline__ v8s pack8(float4 a, float4 b) {
    v8s r;
    r[0] = (short)f2bf(a.x); r[1] = (short)f2bf(a.y);
    r[2] = (short)f2bf(a.z); r[3] = (short)f2bf(a.w);
    r[4] = (short)f2bf(b.x); r[5] = (short)f2bf(b.y);
    r[6] = (short)f2bf(b.z); r[7] = (short)f2bf(b.w);
    return r;
}

// ---------------------------------------------------------------------------
// xp layout: ushort4 xp[b][t][j], j in [0,64): packed bf16 (i,f,g,o) gate
// pre-activations (bias included) for hidden unit j. 134 MB.
//
// Phase 1: block = 16 batches x 16 timesteps (reads 16 contiguous 8KB chunks
// of x). C = W_ih @ x^T per 16x16 tile; M-tiles = batches, rows-in-tile = t.
// Wave w owns gate-tiles gt = cls*4+w so (i,f,g,o) of j = w*16+q*4+r land in
// ONE lane -> ushort4 pack, 32B-segment stores that write-combine to full
// lines. x staged pre-fragmented in LDS (64 KB exactly).
// ---------------------------------------------------------------------------
__global__ __launch_bounds__(256, 2)
void xproj_pack_kernel(const float* __restrict__ x,       // [B,T,D]
                       const float* __restrict__ W_ih,    // [256,128]
                       const float* __restrict__ b_ih,    // [256]
                       const float* __restrict__ b_hh,    // [256]
                       ushort4* __restrict__ xp)          // [b][t][64]
{
    const int tt   = blockIdx.x;      // 0..15 : timesteps tt*16..+15
    const int bb   = blockIdx.y;      // 0..63 : batches  bb*16..+15
    const int tid  = threadIdx.x;
    const int w    = tid >> 6;
    const int lane = tid & 63;
    const int q    = lane >> 4;
    const int ml   = lane & 15;

    // pre-fragmented x tile: Bs[bt][ks][qf][tl][j] -> 16B per (bt,ks,qf,tl)
    __shared__ __align__(16) unsigned short Bs[16][4][4][16][8];  // 64 KB

    // ---- stage x: 32 float4/thread, contiguous within each batch ----
    #pragma unroll
    for (int i = 0; i < 32; ++i) {
        int f4  = i * 256 + tid;          // 8192 float4s
        int bt  = f4 >> 9;                // local batch
        int rem = f4 & 511;
        int tl  = rem >> 5;               // local t
        int c4  = rem & 31;               // float4 within the 128-d row
        float4 v = ((const float4*)(x + ((size_t)(bb * 16 + bt) * T_
                                         + tt * 16 + tl) * D_))[c4];
        short4 s;
        s.x = (short)f2bf(v.x); s.y = (short)f2bf(v.y);
        s.z = (short)f2bf(v.z); s.w = (short)f2bf(v.w);
        int d0 = c4 * 4;
        *(short4*)&Bs[bt][d0 >> 5][(d0 >> 3) & 3][tl][d0 & 7] = s;
    }

    // ---- A-frags: W_ih rows for gt = cls*4+w, plus bias ----
    v8s afr[4][4];        // [cls][ks]
    float bias_r[4][4];   // [cls][r]
    #pragma unroll
    for (int cls = 0; cls < 4; ++cls) {
        const int gt = cls * 4 + w;
        #pragma unroll
        for (int ks = 0; ks < 4; ++ks) {
            const float* p = W_ih + (size_t)(gt * 16 + ml) * D_ + ks * 32 + q * 8;
            afr[cls][ks] = pack8(((const float4*)p)[0], ((const float4*)p)[1]);
        }
        #pragma unroll
        for (int r = 0; r < 4; ++r) {
            const int gr = gt * 16 + q * 4 + r;
            bias_r[cls][r] = b_ih[gr] + b_hh[gr];
        }
    }
    __syncthreads();

    // ---- 4 chunks of 4 M-tiles (batches) ----
    #pragma unroll
    for (int ch = 0; ch < 4; ++ch) {
        v4f acc[4][4];   // [mt][cls]
        #pragma unroll
        for (int mt = 0; mt < 4; ++mt)
            #pragma unroll
            for (int cls = 0; cls < 4; ++cls)
                #pragma unroll
                for (int r = 0; r < 4; ++r)
                    acc[mt][cls][r] = bias_r[cls][r];

        #pragma unroll
        for (int ks = 0; ks < 4; ++ks) {
            v8s bfr[4];
            #pragma unroll
            for (int mt = 0; mt < 4; ++mt)
                bfr[mt] = *(const v8s*)&Bs[ch * 4 + mt][ks][q][ml][0];
            #pragma unroll
            for (int mt = 0; mt < 4; ++mt)
                #pragma unroll
                for (int cls = 0; cls < 4; ++cls)
                    acc[mt][cls] = __builtin_amdgcn_mfma_f32_16x16x32_bf16(
                        afr[cls][ks], bfr[mt], acc[mt][cls], 0, 0, 0);
        }

        // ---- pack + store: (i,f,g,o) for (b, t=tt*16+ml, j=w*16+q*4+r) ----
        #pragma unroll
        for (int mt = 0; mt < 4; ++mt) {
            const int b = bb * 16 + ch * 4 + mt;
            const size_t rowbase = ((size_t)b * T_ + tt * 16 + ml) * 64;
            #pragma unroll
            for (int r = 0; r < 4; ++r) {
                ushort4 p;
                p.x = f2bf(acc[mt][0][r]);   // i
                p.y = f2bf(acc[mt][1][r]);   // f
                p.z = f2bf(acc[mt][2][r]);   // g
                p.w = f2bf(acc[mt][3][r]);   // o
                xp[rowbase + w * 16 + q * 4 + r] = p;
            }
        }
    }
}

// ---------------------------------------------------------------------------
// Phase 2: 64 blocks x 4 waves; block bb owns batches bb*16..+15. Wave w owns
// hcols [16w,16w+16) (gate-tiles cls*4+w). Double-buffered h in LDS -> ONE
// barrier/step; xp prefetch (2 deep) issued right after the consume at the
// top of the step so the barrier drain overlaps a full step of work.
// ---------------------------------------------------------------------------
__global__ __launch_bounds__(256, 1)
void rec2_kernel(const unsigned short* __restrict__ xp,  // [b][t][64] ushort4
                 const float* __restrict__ W_hh,   // [256,64]
                 const float* __restrict__ W1,     // [32,64]
                 const float* __restrict__ b1,     // [32]
                 const float* __restrict__ W2,     // [1,32]
                 const float* __restrict__ b2,     // [1]
                 float* __restrict__ out)          // [1024]
{
    const int bb   = blockIdx.x;
    const int tid  = threadIdx.x;
    const int w    = tid >> 6;
    const int lane = tid & 63;
    const int q    = lane >> 4;
    const int ml   = lane & 15;

    __shared__ __align__(16) unsigned short hbf[2][16][72];  // double-buffered h
    __shared__ __align__(16) float hf[16][68];               // final h f32
    __shared__ __align__(16) float ys[16][36];               // head hidden

    // ---- W_hh A-frags [cls][ks] ----
    v8s whh[4][2];
    #pragma unroll
    for (int cls = 0; cls < 4; ++cls) {
        const int gr = (cls * 4 + w) * 16 + ml;
        #pragma unroll
        for (int ks = 0; ks < 2; ++ks) {
            const float* p = W_hh + (size_t)gr * H_ + ks * 32 + q * 8;
            whh[cls][ks] = pack8(((const float4*)p)[0], ((const float4*)p)[1]);
        }
    }

    // zero both h slots (2*16*72 = 2304 shorts = 1152 dwords)
    for (int i = tid; i < 1152; i += 256) ((unsigned*)hbf)[i] = 0u;

    float c[4] = {0.f, 0.f, 0.f, 0.f};
    float hlast[4] = {0.f, 0.f, 0.f, 0.f};

    // lane's xp stream: batch = bb*16+ml, j = w*16+q*4 .. +3 -> 32B per step
    const unsigned short* lanep =
        xp + (((size_t)(bb * 16 + ml) * T_) * 64 + (w * 16 + q * 4)) * 4;
    // per-step stride: 64*4 = 256 ushorts (512 B)

    uint4 pf[2][2];
    pf[0][0] = ((const uint4*)(lanep))[0];
    pf[0][1] = ((const uint4*)(lanep))[1];
    pf[1][0] = ((const uint4*)(lanep + 256))[0];
    pf[1][1] = ((const uint4*)(lanep + 256))[1];

    __syncthreads();   // h zero-init visible

    for (int t = 0; t < T_; ++t) {
        const int cur = t & 1;
        // ---- consume prefetch: acc init (bias+xproj already summed) ----
        v4f acc[4];
        {
            uint4 A = pf[cur][0], Bv = pf[cur][1];
            // r0: A.x = f<<16|i, A.y = o<<16|g ; r1: A.z, A.w ; r2/r3 in Bv
            acc[0][0] = __uint_as_float(A.x << 16);
            acc[1][0] = __uint_as_float(A.x & 0xffff0000u);
            acc[2][0] = __uint_as_float(A.y << 16);
            acc[3][0] = __uint_as_float(A.y & 0xffff0000u);
            acc[0][1] = __uint_as_float(A.z << 16);
            acc[1][1] = __uint_as_float(A.z & 0xffff0000u);
            acc[2][1] = __uint_as_float(A.w << 16);
            acc[3][1] = __uint_as_float(A.w & 0xffff0000u);
            acc[0][2] = __uint_as_float(Bv.x << 16);
            acc[1][2] = __uint_as_float(Bv.x & 0xffff0000u);
            acc[2][2] = __uint_as_float(Bv.y << 16);
            acc[3][2] = __uint_as_float(Bv.y & 0xffff0000u);
            acc[0][3] = __uint_as_float(Bv.z << 16);
            acc[1][3] = __uint_as_float(Bv.z & 0xffff0000u);
            acc[2][3] = __uint_as_float(Bv.w << 16);
            acc[3][3] = __uint_as_float(Bv.w & 0xffff0000u);
        }
        // ---- prefetch t+2 (issued early; drained at the END-of-step barrier
        //      after ~a full step of work) ----
        {
            const int tp = (t + 2 < T_) ? t + 2 : T_ - 1;
            const unsigned short* p = lanep + (size_t)tp * 256;
            pf[cur][0] = ((const uint4*)p)[0];
            pf[cur][1] = ((const uint4*)p)[1];
        }
        // ---- recurrent MFMA on h(t) from slot cur ----
        v8s h0 = *(const v8s*)&hbf[cur][ml][q * 8];
        v8s h1 = *(const v8s*)&hbf[cur][ml][32 + q * 8];
        #pragma unroll
        for (int cls = 0; cls < 4; ++cls) {
            acc[cls] = __builtin_amdgcn_mfma_f32_16x16x32_bf16(
                whh[cls][0], h0, acc[cls], 0, 0, 0);
            acc[cls] = __builtin_amdgcn_mfma_f32_16x16x32_bf16(
                whh[cls][1], h1, acc[cls], 0, 0, 0);
        }
        // ---- elementwise: (batch = bb*16+ml, hcol = 16w+q*4+r) ----
        #pragma unroll
        for (int r = 0; r < 4; ++r) {
            float gi = sigmoidf_(acc[0][r]);
            float gf = sigmoidf_(acc[1][r]);
            float gg = tanhf_(acc[2][r]);
            float go = sigmoidf_(acc[3][r]);
            c[r] = fmaf(gf, c[r], gi * gg);
            hlast[r] = go * tanhf_(c[r]);
        }
        // ---- write h(t+1) to the other slot ----
        ushort4 hp;
        hp.x = f2bf(hlast[0]); hp.y = f2bf(hlast[1]);
        hp.z = f2bf(hlast[2]); hp.w = f2bf(hlast[3]);
        *(ushort4*)&hbf[1 - cur][ml][w * 16 + q * 4] = hp;

        __syncthreads();   // single barrier: publishes h(t+1); WAR-safe
    }

    // ---- head ----
    {
        float4 hv; hv.x = hlast[0]; hv.y = hlast[1]; hv.z = hlast[2]; hv.w = hlast[3];
        *(float4*)&hf[ml][w * 16 + q * 4] = hv;
    }
    __syncthreads();
    {
        const int bloc = tid & 15, jj = tid >> 4;
        #pragma unroll
        for (int j2 = 0; j2 < 2; ++j2) {
            const int j = jj + j2 * 16;
            float acc = b1[j];
            const float4* w1r = (const float4*)(W1 + (size_t)j * H_);
            #pragma unroll
            for (int k4 = 0; k4 < 16; ++k4) {
                float4 h4 = *(const float4*)&hf[bloc][k4 * 4];
                float4 w4 = w1r[k4];
                acc = fmaf(w4.x, h4.x, acc); acc = fmaf(w4.y, h4.y, acc);
                acc = fmaf(w4.z, h4.z, acc); acc = fmaf(w4.w, h4.w, acc);
            }
            ys[bloc][j] = fmaxf(acc, 0.0f);
        }
    }
    __syncthreads();
    if (tid < 16) {
        float a = b2[0];
        #pragma unroll
        for (int j = 0; j < 32; ++j) a = fmaf(W2[j], ys[tid][j], a);
        out[bb * 16 + tid] = sigmoidf_(a);
    }
}

// ---------------------------------------------------------------------------
// Fallback: round-1 fused fp32 kernel (used only if workspace too small).
// ---------------------------------------------------------------------------
__global__ __launch_bounds__(256, 2)
void lstm_fused_kernel(const float* __restrict__ x,
                       const float* __restrict__ W_ih,
                       const float* __restrict__ W_hh,
                       const float* __restrict__ b_ih,
                       const float* __restrict__ b_hh,
                       const float* __restrict__ W1,
                       const float* __restrict__ b1,
                       const float* __restrict__ W2,
                       const float* __restrict__ b2,
                       float* __restrict__ out)
{
    const int b = blockIdx.x;
    const int g = threadIdx.x;

    __shared__ __align__(16) float xs[D_];
    __shared__ __align__(16) float hs[H_];
    __shared__ __align__(16) float gates[G_];
    __shared__ __align__(16) float yss[32];

    float wih[D_];
    float whhr[H_];
    {
        const float4* wr = (const float4*)(W_ih + (size_t)g * D_);
        #pragma unroll
        for (int k = 0; k < D_ / 4; ++k) {
            float4 v = wr[k];
            wih[4*k+0] = v.x; wih[4*k+1] = v.y;
            wih[4*k+2] = v.z; wih[4*k+3] = v.w;
        }
    }
    {
        const float4* wr = (const float4*)(W_hh + (size_t)g * H_);
        #pragma unroll
        for (int k = 0; k < H_ / 4; ++k) {
            float4 v = wr[k];
            whhr[4*k+0] = v.x; whhr[4*k+1] = v.y;
            whhr[4*k+2] = v.z; whhr[4*k+3] = v.w;
        }
    }
    const float bg  = b_ih[g] + b_hh[g];
    const int   cls = g >> 6;

    float c = 0.0f;
    if (g < H_) hs[g] = 0.0f;

    const float* __restrict__ xrow = x + (size_t)b * T_ * D_;

    for (int t = 0; t < T_; ++t) {
        if (g < D_) xs[g] = xrow[(size_t)t * D_ + g];
        __syncthreads();

        float a0 = bg, a1 = 0.f, a2 = 0.f, a3 = 0.f;
        const float4* xs4 = (const float4*)xs;
        #pragma unroll
        for (int k = 0; k < D_ / 4; ++k) {
            float4 v = xs4[k];
            a0 = fmaf(wih[4*k+0], v.x, a0);
            a1 = fmaf(wih[4*k+1], v.y, a1);
            a2 = fmaf(wih[4*k+2], v.z, a2);
            a3 = fmaf(wih[4*k+3], v.w, a3);
        }
        const float4* hs4 = (const float4*)hs;
        #pragma unroll
        for (int k = 0; k < H_ / 4; ++k) {
            float4 v = hs4[k];
            a0 = fmaf(whhr[4*k+0], v.x, a0);
            a1 = fmaf(whhr[4*k+1], v.y, a1);
            a2 = fmaf(whhr[4*k+2], v.z, a2);
            a3 = fmaf(whhr[4*k+3], v.w, a3);
        }
        float acc = (a0 + a1) + (a2 + a3);
        gates[g] = (cls == 2) ? tanhf_(acc) : sigmoidf_(acc);
        __syncthreads();

        if (g < H_) {
            float gi = gates[g];
            float gf = gates[H_ + g];
            float gg = gates[2 * H_ + g];
            float go = gates[3 * H_ + g];
            c = fmaf(gf, c, gi * gg);
            hs[g] = go * tanhf_(c);
        }
    }
    __syncthreads();

    if (g < 32) {
        float acc = b1[g];
        const float* w1r = W1 + g * H_;
        #pragma unroll
        for (int k = 0; k < H_; ++k) acc = fmaf(w1r[k], hs[k], acc);
        yss[g] = fmaxf(acc, 0.0f);
    }
    __syncthreads();
    if (g == 0) {
        float acc = b2[0];
        #pragma unroll
        for (int k = 0; k < 32; ++k) acc = fmaf(W2[k], yss[k], acc);
        out[b] = sigmoidf_(acc);
    }
}

extern "C" void kernel_launch(void* const* d_in, const int* in_sizes, int n_in,
                              void* d_out, int out_size, void* d_ws, size_t ws_size,
                              hipStream_t stream) {
    const float* x    = (const float*)d_in[0];
    const float* W_ih = (const float*)d_in[1];
    const float* W_hh = (const float*)d_in[2];
    const float* b_ih = (const float*)d_in[3];
    const float* b_hh = (const float*)d_in[4];
    const float* W1   = (const float*)d_in[5];
    const float* b1   = (const float*)d_in[6];
    const float* W2   = (const float*)d_in[7];
    const float* b2   = (const float*)d_in[8];
    float* out = (float*)d_out;

    const size_t xp_bytes = (size_t)M_ * G_ * sizeof(unsigned short);  // 134 MB

    if (ws_size >= xp_bytes) {
        ushort4* xp = (ushort4*)d_ws;
        xproj_pack_kernel<<<dim3(16, 64), dim3(256), 0, stream>>>(
            x, W_ih, b_ih, b_hh, xp);
        rec2_kernel<<<dim3(64), dim3(256), 0, stream>>>(
            (const unsigned short*)xp, W_hh, W1, b1, W2, b2, out);
    } else {
        lstm_fused_kernel<<<dim3(B_), dim3(256), 0, stream>>>(
            x, W_ih, W_hh, b_ih, b_hh, W1, b1, W2, b2, out);
    }
}